// Round 14
// baseline (1015.186 us; speedup 1.0000x reference)
//
#include <hip/hip_runtime.h>
#include <hip/hip_fp16.h>

#define B_ 256
#define T_ 512
#define H_ 128
#define M_ (B_ * T_)  // 131072 rows

typedef _Float16 f16x8 __attribute__((ext_vector_type(8)));
typedef float    f32x4 __attribute__((ext_vector_type(4)));

__device__ __forceinline__ float rcp_f(float a) { return __builtin_amdgcn_rcpf(a); }
__device__ __forceinline__ float sigmoid_f(float a) { return rcp_f(1.f + __expf(-a)); }
__device__ __forceinline__ float tanh_f(float a) { return 1.f - 2.f * rcp_f(__expf(2.f * a) + 1.f); }

__device__ __forceinline__ void lds_barrier() {
    asm volatile("s_waitcnt lgkmcnt(0)\n\ts_barrier" ::: "memory");
}
#define PINV(X) asm volatile("" : "+v"(X))

__device__ __forceinline__ __half cell_update(float g0, float g1, float g2, float g3, float& c) {
    float iv = sigmoid_f(g0), fv = sigmoid_f(g1);
    float gv = tanh_f(g2),   ov = sigmoid_f(g3);
    c = fv * c + iv * gv;
    return __float2half(ov * tanh_f(c));
}

#define MFMA16(A, BV, C) __builtin_amdgcn_mfma_f32_16x16x32_f16((A), (BV), (C), 0, 0, 0)
#define MF4(AV, WARR, KT) \
    ac0 = MFMA16(AV, WARR[0][KT], ac0); \
    ac1 = MFMA16(AV, WARR[1][KT], ac1); \
    ac2 = MFMA16(AV, WARR[2][KT], ac2); \
    ac3 = MFMA16(AV, WARR[3][KT], ac3);
#define MF4P(AV, KT) \
    p0_ = MFMA16(AV, wiv[0][KT], p0_); \
    p1_ = MFMA16(AV, wiv[1][KT], p1_); \
    p2_ = MFMA16(AV, wiv[2][KT], p2_); \
    p3_ = MFMA16(AV, wiv[3][KT], p3_);

// ---------- one-time conversions ----------
__global__ __launch_bounds__(256)
void convert_kernel(const float* __restrict__ Wih0, const float* __restrict__ bih0, const float* __restrict__ bhh0,
                    const float* __restrict__ Whh0, const float* __restrict__ Wih1, const float* __restrict__ Whh1,
                    const float* __restrict__ bih1, const float* __restrict__ bhh1,
                    const float* __restrict__ Wl, const float* __restrict__ bl,
                    const float* __restrict__ Wo, const float* __restrict__ bo,
                    __half* __restrict__ W0b, __half* __restrict__ W1b,
                    __half* __restrict__ Whh0h, __half* __restrict__ Whh1h,
                    __half* __restrict__ Wc16, float* __restrict__ b0, float* __restrict__ b1,
                    float* __restrict__ bc)
{
    const int tid = threadIdx.x, bid = blockIdx.x;
    if (bid == 0) {
        for (int i = tid; i < 512; i += 256) { b0[i] = bih0[i] + bhh0[i]; b1[i] = bih1[i] + bhh1[i]; }
        for (int i = tid; i < 512 * 32; i += 256) {
            int r = i >> 5, k = i & 31;
            W0b[i] = __float2half(k < 30 ? Wih0[r * 30 + k] : 0.f);
        }
        for (int i = tid; i < 64 * 128; i += 256) {
            int j = i >> 7, k = i & 127;
            float a = 0.f;
            if (j < 63) for (int m = 0; m < 84; ++m) a += Wo[j * 84 + m] * Wl[m * 128 + k];
            Wc16[i] = __float2half(a);
        }
        if (tid < 64) {
            float a = 0.f;
            if (tid < 63) { a = bo[tid]; for (int m = 0; m < 84; ++m) a += Wo[tid * 84 + m] * bl[m]; }
            bc[tid] = a;
        }
    } else if (bid == 1) {
        for (int i = tid; i < 512 * 128; i += 256) W1b[i] = __float2half(Wih1[i]);
    } else if (bid == 2) {
        for (int i = tid; i < 512 * 128; i += 256) Whh0h[i] = __float2half(Whh0[i]);
    } else {
        for (int i = tid; i < 512 * 128; i += 256) Whh1h[i] = __float2half(Whh1[i]);
    }
}

// ---------- both layers in one block: 16-tick in-block pipeline, LDS-only comms ----------
// waves 0-3: layer-0 rec at tick t; waves 4-7: layer-1 rec at t-8.
// All 8 waves burst input projections (own 16-unit slice): xp0 (K=32, from staged x)
// into gb0; xp1 (K=128, from 8-slot LDS h1 ring) into gb1. 4-step chunks, double-buffered.
// No flags, no polls, no sc, no vmcnt waits — one lds_barrier per tick.
__global__ __launch_bounds__(512, 1)
void lstm_onecu(const float* __restrict__ x,
                const __half* __restrict__ W0b, const __half* __restrict__ Whh0h,
                const __half* __restrict__ W1b, const __half* __restrict__ Whh1h,
                const float* __restrict__ b0, const float* __restrict__ b1,
                __half* __restrict__ h2g)
{
    const int g = blockIdx.x;            // batches 4g..4g+3
    const int tid = threadIdx.x;
    const int w = tid >> 6;
    const int lane = tid & 63;
    const int l15 = lane & 15, qg = lane >> 4;
    const int r = l15 >> 2;
    const bool isA = w < 4;
    const int pw = isA ? w : w - 4;
    const int j0 = (2 * pw) * 16 + l15;  // rec tiles
    const int j1 = (2 * pw + 1) * 16 + l15;
    const int jv = w * 16 + l15;         // burst tile (all 8 waves cover 128 units)

    __shared__ __align__(16) char hist[8 * 1280];     // h1 ring: 8 steps x [4b x 320B]
    __shared__ __align__(16) char hbuf_s[2][1280];    // layer-1 h tile
    __shared__ __align__(16) __half xl[4][129][32];   // x chunk (128 steps)
    __shared__ __align__(16) char gb0[2 * 16 * 1040]; // layer-0 gates, 2 x 4-step chunks
    __shared__ __align__(16) char gb1[2 * 16 * 1040]; // layer-1 gates

    const int ro0 = r * 320 + 0 * 64 + qg * 16;
    const int ro1 = r * 320 + 1 * 64 + qg * 16;
    const int ro2 = r * 320 + 2 * 64 + qg * 16;
    const int ro3 = r * 320 + 3 * 64 + qg * 16;
    const char* xlb = (const char*)xl;

    // weights: rec Whh (this wave's layer, 2 tiles) + burst slices
    const __half* Whh = isA ? Whh0h : Whh1h;
    f16x8 wr0[4][4], wr1[4][4], wiv[4][4], wxv[4];
    float b0v[4], b1v[4];
#pragma unroll
    for (int q = 0; q < 4; ++q) {
        b0v[q] = b0[q * 128 + jv];
        b1v[q] = b1[q * 128 + jv];
        wxv[q] = *reinterpret_cast<const f16x8*>(W0b + (size_t)(q * 128 + jv) * 32 + qg * 8);
        PINV(wxv[q]);
#pragma unroll
        for (int kt = 0; kt < 4; ++kt) {
            wr0[q][kt] = *reinterpret_cast<const f16x8*>(Whh + (size_t)(q * 128 + j0) * 128 + kt * 32 + qg * 8);
            wr1[q][kt] = *reinterpret_cast<const f16x8*>(Whh + (size_t)(q * 128 + j1) * 128 + kt * 32 + qg * 8);
            wiv[q][kt] = *reinterpret_cast<const f16x8*>(W1b + (size_t)(q * 128 + jv) * 128 + kt * 32 + qg * 8);
            PINV(wr0[q][kt]); PINV(wr1[q][kt]); PINV(wiv[q][kt]);
        }
    }

    // zero h1 ring, h2 tile, x pad cols
    for (int i = tid; i < 2560; i += 512) ((unsigned*)hist)[i] = 0;
    for (int i = tid; i < 320; i += 512) ((unsigned*)hbuf_s[0])[i] = 0;
    for (int idx = tid; idx < 1024; idx += 512) {
        int b4 = idx >> 8, rest = idx & 255;
        xl[b4][rest >> 1][30 + (rest & 1)] = __float2half(0.f);
    }

#define STAGEBODY(XC) do {                                                      \
    _Pragma("unroll 1")                                                         \
    for (int b4_ = 0; b4_ < 4; ++b4_) {                                         \
        const float* src_ = x + ((size_t)(g * 4 + b4_) * T_ + (XC) * 128) * 30; \
        for (int idx_ = tid; idx_ < 3840; idx_ += 512) {                        \
            int tt_ = idx_ / 30, ii_ = idx_ - tt_ * 30;                         \
            xl[b4_][tt_][ii_] = __float2half(src_[idx_]);                       \
        }                                                                       \
    }                                                                           \
} while (0)

// xp0 chunk CC (steps 4CC..4CC+3, 16 rows): 4 MFMA, gates -> gb0[CC&1]
#define XP0PIECE(CC) do {                                                       \
    const int sl_ = l15 >> 2, bb_ = l15 & 3;                                    \
    f16x8 ax_ = *(const f16x8*)(xlb + bb_ * 8256 + (((CC) * 4 + sl_) & 127) * 64 + qg * 16); \
    f32x4 p0_ = (f32x4){b0v[0], b0v[0], b0v[0], b0v[0]};                        \
    f32x4 p1_ = (f32x4){b0v[1], b0v[1], b0v[1], b0v[1]};                        \
    f32x4 p2_ = (f32x4){b0v[2], b0v[2], b0v[2], b0v[2]};                        \
    f32x4 p3_ = (f32x4){b0v[3], b0v[3], b0v[3], b0v[3]};                        \
    p0_ = MFMA16(ax_, wxv[0], p0_); p1_ = MFMA16(ax_, wxv[1], p1_);             \
    p2_ = MFMA16(ax_, wxv[2], p2_); p3_ = MFMA16(ax_, wxv[3], p3_);             \
    char* gd_ = gb0 + ((CC) & 1) * 16640 + 8 * jv;                              \
    _Pragma("unroll")                                                           \
    for (int r4_ = 0; r4_ < 4; ++r4_) {                                         \
        const int ro_ = qg * 4 + r4_;                                           \
        __half2 lo_ = __floats2half2_rn(p0_[r4_], p1_[r4_]);                    \
        __half2 hi_ = __floats2half2_rn(p2_[r4_], p3_[r4_]);                    \
        uint2 pk_;                                                              \
        pk_.x = __builtin_bit_cast(unsigned, lo_);                              \
        pk_.y = __builtin_bit_cast(unsigned, hi_);                              \
        *(uint2*)(gd_ + ro_ * 1040) = pk_;                                      \
    }                                                                           \
} while (0)

// xp1 chunk CC (h1 steps 4CC..4CC+3 from ring): 16 MFMA, gates -> gb1[CC&1]
#define XP1PIECE(CC) do {                                                       \
    const int sl_ = l15 >> 2, bb_ = l15 & 3;                                    \
    const char* ap_ = hist + (((CC) * 4 + sl_) & 7) * 1280 + bb_ * 320 + qg * 16; \
    f16x8 h0_ = *(const f16x8*)(ap_);                                           \
    f16x8 h1_ = *(const f16x8*)(ap_ + 64);                                      \
    f16x8 h2_ = *(const f16x8*)(ap_ + 128);                                     \
    f16x8 h3_ = *(const f16x8*)(ap_ + 192);                                     \
    f32x4 p0_ = (f32x4){b1v[0], b1v[0], b1v[0], b1v[0]};                        \
    f32x4 p1_ = (f32x4){b1v[1], b1v[1], b1v[1], b1v[1]};                        \
    f32x4 p2_ = (f32x4){b1v[2], b1v[2], b1v[2], b1v[2]};                        \
    f32x4 p3_ = (f32x4){b1v[3], b1v[3], b1v[3], b1v[3]};                        \
    MF4P(h0_, 0) MF4P(h1_, 1) MF4P(h2_, 2) MF4P(h3_, 3)                         \
    char* gd_ = gb1 + ((CC) & 1) * 16640 + 8 * jv;                              \
    _Pragma("unroll")                                                           \
    for (int r4_ = 0; r4_ < 4; ++r4_) {                                         \
        const int ro_ = qg * 4 + r4_;                                           \
        __half2 lo_ = __floats2half2_rn(p0_[r4_], p1_[r4_]);                    \
        __half2 hi_ = __floats2half2_rn(p2_[r4_], p3_[r4_]);                    \
        uint2 pk_;                                                              \
        pk_.x = __builtin_bit_cast(unsigned, lo_);                              \
        pk_.y = __builtin_bit_cast(unsigned, hi_);                              \
        *(uint2*)(gd_ + ro_ * 1040) = pk_;                                      \
    }                                                                           \
} while (0)

#define L0STEP(TT) do {                                                         \
    const int t_ = (TT);                                                        \
    const char* rp_ = hist + ((t_ + 7) & 7) * 1280;                             \
    char* wp_ = hist + (t_ & 7) * 1280;                                         \
    const char* gq_ = gb0 + ((t_ >> 2) & 1) * 16640 + ((t_ & 3) * 4 + qg) * 1040; \
    uint2 x0_ = *(const uint2*)(gq_ + 8 * j0);                                  \
    uint2 x1_ = *(const uint2*)(gq_ + 8 * j1);                                  \
    f16x8 a0_ = *(const f16x8*)(rp_ + ro0);                                     \
    f16x8 a1_ = *(const f16x8*)(rp_ + ro1);                                     \
    f16x8 a2_ = *(const f16x8*)(rp_ + ro2);                                     \
    f16x8 a3_ = *(const f16x8*)(rp_ + ro3);                                     \
    {   float2 flo = __half22float2(__builtin_bit_cast(__half2, x0_.x));        \
        float2 fhi = __half22float2(__builtin_bit_cast(__half2, x0_.y));        \
        f32x4 ac0 = (f32x4){flo.x, 0.f, 0.f, 0.f};                              \
        f32x4 ac1 = (f32x4){flo.y, 0.f, 0.f, 0.f};                              \
        f32x4 ac2 = (f32x4){fhi.x, 0.f, 0.f, 0.f};                              \
        f32x4 ac3 = (f32x4){fhi.y, 0.f, 0.f, 0.f};                              \
        MF4(a0_, wr0, 0) MF4(a1_, wr0, 1) MF4(a2_, wr0, 2) MF4(a3_, wr0, 3)     \
        __half hh_ = cell_update(ac0[0], ac1[0], ac2[0], ac3[0], c0);           \
        *(__half*)(wp_ + qg * 320 + j0 * 2) = hh_; }                            \
    {   float2 flo = __half22float2(__builtin_bit_cast(__half2, x1_.x));        \
        float2 fhi = __half22float2(__builtin_bit_cast(__half2, x1_.y));        \
        f32x4 ac0 = (f32x4){flo.x, 0.f, 0.f, 0.f};                              \
        f32x4 ac1 = (f32x4){flo.y, 0.f, 0.f, 0.f};                              \
        f32x4 ac2 = (f32x4){fhi.x, 0.f, 0.f, 0.f};                              \
        f32x4 ac3 = (f32x4){fhi.y, 0.f, 0.f, 0.f};                              \
        MF4(a0_, wr1, 0) MF4(a1_, wr1, 1) MF4(a2_, wr1, 2) MF4(a3_, wr1, 3)     \
        __half hh_ = cell_update(ac0[0], ac1[0], ac2[0], ac3[0], c1);           \
        *(__half*)(wp_ + qg * 320 + j1 * 2) = hh_; }                            \
} while (0)

#define L1STEP(SS, RP, WP) do {                                                 \
    const int s_ = (SS);                                                        \
    const char* gq_ = gb1 + ((s_ >> 2) & 1) * 16640 + ((s_ & 3) * 4 + qg) * 1040; \
    uint2 x0_ = *(const uint2*)(gq_ + 8 * j0);                                  \
    uint2 x1_ = *(const uint2*)(gq_ + 8 * j1);                                  \
    f16x8 a0_ = *(const f16x8*)((RP) + ro0);                                    \
    f16x8 a1_ = *(const f16x8*)((RP) + ro1);                                    \
    f16x8 a2_ = *(const f16x8*)((RP) + ro2);                                    \
    f16x8 a3_ = *(const f16x8*)((RP) + ro3);                                    \
    {   float2 flo = __half22float2(__builtin_bit_cast(__half2, x0_.x));        \
        float2 fhi = __half22float2(__builtin_bit_cast(__half2, x0_.y));        \
        f32x4 ac0 = (f32x4){flo.x, 0.f, 0.f, 0.f};                              \
        f32x4 ac1 = (f32x4){flo.y, 0.f, 0.f, 0.f};                              \
        f32x4 ac2 = (f32x4){fhi.x, 0.f, 0.f, 0.f};                              \
        f32x4 ac3 = (f32x4){fhi.y, 0.f, 0.f, 0.f};                              \
        MF4(a0_, wr0, 0) MF4(a1_, wr0, 1) MF4(a2_, wr0, 2) MF4(a3_, wr0, 3)     \
        __half hh_ = cell_update(ac0[0], ac1[0], ac2[0], ac3[0], c0);           \
        *(__half*)((WP) + qg * 320 + j0 * 2) = hh_;                             \
        h2p0[(size_t)s_ * H_] = hh_; }                                          \
    {   float2 flo = __half22float2(__builtin_bit_cast(__half2, x1_.x));        \
        float2 fhi = __half22float2(__builtin_bit_cast(__half2, x1_.y));        \
        f32x4 ac0 = (f32x4){flo.x, 0.f, 0.f, 0.f};                              \
        f32x4 ac1 = (f32x4){flo.y, 0.f, 0.f, 0.f};                              \
        f32x4 ac2 = (f32x4){fhi.x, 0.f, 0.f, 0.f};                              \
        f32x4 ac3 = (f32x4){fhi.y, 0.f, 0.f, 0.f};                              \
        MF4(a0_, wr1, 0) MF4(a1_, wr1, 1) MF4(a2_, wr1, 2) MF4(a3_, wr1, 3)     \
        __half hh_ = cell_update(ac0[0], ac1[0], ac2[0], ac3[0], c1);           \
        *(__half*)((WP) + qg * 320 + j1 * 2) = hh_;                             \
        h2p1[(size_t)s_ * H_] = hh_; }                                          \
} while (0)

    float c0 = 0.f, c1 = 0.f;
    __half* h2p0 = h2g + ((size_t)(g * 4 + qg) * T_) * H_ + j0;
    __half* h2p1 = h2g + ((size_t)(g * 4 + qg) * T_) * H_ + j1;

    __syncthreads();           // LDS zero-init visible
    STAGEBODY(0);              // x chunk 0
    __syncthreads();
    XP0PIECE(0);               // prime gb0 chunk 0
    lds_barrier();

#pragma unroll 1
    for (int tk = 0; tk < 520; tk += 2) {
        // burst pieces (even ticks): xp0 at tk%4==0 (chunk (tk>>2)+1), xp1 at tk%4==2
        if ((tk & 3) == 0) {
            if (tk <= 504) XP0PIECE((tk >> 2) + 1);
        } else {
            const int cc1_ = (tk - 6) >> 2;
            if (tk >= 6 && cc1_ < 128) XP1PIECE(cc1_);
        }
        // stage next x chunk (8 ticks before the bursts need it)
        if (tk < 504 && ((tk + 8) & 127) == 0) {
            __syncthreads();
            STAGEBODY((tk + 8) >> 7);
            __syncthreads();
        }
        // even tick
        if (isA) { if (tk < 512) L0STEP(tk); }
        else     { if (tk >= 8) L1STEP(tk - 8, hbuf_s[0], hbuf_s[1]); }
        lds_barrier();
        // odd tick
        if (isA) { if (tk + 1 < 512) L0STEP(tk + 1); }
        else     { if (tk >= 8) L1STEP(tk - 7, hbuf_s[1], hbuf_s[0]); }
        lds_barrier();
    }
}

// ---------- head: out = h2 @ Wc^T + bc (63 cols, f32) ----------
__global__ __launch_bounds__(256, 4)
void head_kernel(const __half* __restrict__ in, const __half* __restrict__ W16,
                 const float* __restrict__ bias, float* __restrict__ outp)
{
    constexpr int KK = 128;
    const int lane = threadIdx.x & 63;
    const int wn = threadIdx.x >> 6;
    const int rowbase = blockIdx.x * 64;
    const int colbase = wn * 16;
    const int l15 = lane & 15, lk = (lane >> 4) * 8;

    float bcol = bias[colbase + l15];
    f32x4 acc[4];
#pragma unroll
    for (int rt = 0; rt < 4; ++rt) acc[rt] = (f32x4){0.f, 0.f, 0.f, 0.f};

#pragma unroll
    for (int kt = 0; kt < 4; ++kt) {
        f16x8 bv = *reinterpret_cast<const f16x8*>(W16 + (size_t)(colbase + l15) * KK + kt * 32 + lk);
#pragma unroll
        for (int rt = 0; rt < 4; ++rt) {
            f16x8 a = *reinterpret_cast<const f16x8*>(in + (size_t)(rowbase + rt * 16 + l15) * KK + kt * 32 + lk);
            acc[rt] = __builtin_amdgcn_mfma_f32_16x16x32_f16(a, bv, acc[rt], 0, 0, 0);
        }
    }
    const int col = colbase + l15;
#pragma unroll
    for (int rt = 0; rt < 4; ++rt)
#pragma unroll
        for (int rr = 0; rr < 4; ++rr) {
            const int row = rowbase + rt * 16 + (lane >> 4) * 4 + rr;
            if (col < 63) outp[(size_t)row * 63 + col] = acc[rt][rr] + bcol;
        }
}

extern "C" void kernel_launch(void* const* d_in, const int* in_sizes, int n_in,
                              void* d_out, int out_size, void* d_ws, size_t ws_size,
                              hipStream_t stream)
{
    const float* x    = (const float*)d_in[0];
    const float* Wih0 = (const float*)d_in[1];
    const float* Whh0 = (const float*)d_in[2];
    const float* bih0 = (const float*)d_in[3];
    const float* bhh0 = (const float*)d_in[4];
    const float* Wih1 = (const float*)d_in[5];
    const float* Whh1 = (const float*)d_in[6];
    const float* bih1 = (const float*)d_in[7];
    const float* bhh1 = (const float*)d_in[8];
    const float* Wl   = (const float*)d_in[9];
    const float* bl   = (const float*)d_in[10];
    const float* Wo   = (const float*)d_in[11];
    const float* bo   = (const float*)d_in[12];
    float* out = (float*)d_out;

    char* ws = (char*)d_ws;
    size_t off = 0;
    auto carve = [&](size_t bytes) { void* p = ws + off; off += (bytes + 255) & ~(size_t)255; return p; };
    __half* h2    = (__half*)carve((size_t)M_ * 128 * 2);   // 33.5 MB
    __half* W0b   = (__half*)carve(512 * 32 * 2);
    __half* W1b   = (__half*)carve(512 * 128 * 2);
    __half* Whh0h = (__half*)carve(512 * 128 * 2);
    __half* Whh1h = (__half*)carve(512 * 128 * 2);
    __half* Wc16  = (__half*)carve(64 * 128 * 2);
    float*  b0    = (float*)carve(512 * 4);
    float*  b1    = (float*)carve(512 * 4);
    float*  bc    = (float*)carve(64 * 4);

    hipLaunchKernelGGL(convert_kernel, dim3(4), dim3(256), 0, stream,
                       Wih0, bih0, bhh0, Whh0, Wih1, Whh1, bih1, bhh1, Wl, bl, Wo, bo,
                       W0b, W1b, Whh0h, Whh1h, Wc16, b0, b1, bc);

    hipLaunchKernelGGL(lstm_onecu, dim3(64), dim3(512), 0, stream,
                       x, W0b, Whh0h, W1b, Whh1h, b0, b1, h2);

    hipLaunchKernelGGL(head_kernel, dim3(M_ / 64), dim3(256), 0, stream,
                       h2, Wc16, bc, out);
}

// Round 15
// 382.376 us; speedup vs baseline: 2.6549x; 2.6549x over previous
//
#include <hip/hip_runtime.h>
#include <hip/hip_fp16.h>

#define B_ 256
#define T_ 512
#define H_ 128
#define M_ (B_ * T_)  // 131072 rows

typedef _Float16 f16x8 __attribute__((ext_vector_type(8)));
typedef float    f32x4 __attribute__((ext_vector_type(4)));

__device__ __forceinline__ float rcp_f(float a) { return __builtin_amdgcn_rcpf(a); }
__device__ __forceinline__ float sigmoid_f(float a) { return rcp_f(1.f + __expf(-a)); }
__device__ __forceinline__ float tanh_f(float a) { return 1.f - 2.f * rcp_f(__expf(2.f * a) + 1.f); }

// LDS-only barrier: global loads/stores stay in flight (T4: never vmcnt(0) per step).
__device__ __forceinline__ void lds_barrier() {
    asm volatile("s_waitcnt lgkmcnt(0)\n\ts_barrier" ::: "memory");
}

#define PINV(X) asm volatile("" : "+v"(X))

__device__ __forceinline__ __half cell_update(float g0, float g1, float g2, float g3, float& c) {
    float iv = sigmoid_f(g0), fv = sigmoid_f(g1);
    float gv = tanh_f(g2),   ov = sigmoid_f(g3);
    c = fv * c + iv * gv;
    return __float2half(ov * tanh_f(c));
}

// ---- device-visible (cross-XCD via L3) memory ops: sc0 sc1 ----
__device__ __forceinline__ void store_dwordx2_sc(uint64_t addr, uint2 v) {
    asm volatile("global_store_dwordx2 %0, %1, off sc0 sc1" :: "v"(addr), "v"(v) : "memory");
}
__device__ __forceinline__ void store_flag_sc(uint64_t addr, unsigned v) {
    asm volatile("global_store_dword %0, %1, off sc0 sc1" :: "v"(addr), "v"(v) : "memory");
}
__device__ __forceinline__ unsigned load_flag_sc(uint64_t addr) {
    unsigned v;
    asm volatile("global_load_dword %0, %1, off sc0 sc1\n\ts_waitcnt vmcnt(0)"
                 : "=v"(v) : "v"(addr) : "memory");
    return v;
}
#define LOAD8_SC(dst, addr) \
    asm volatile("global_load_dwordx2 %0, %1, off sc0 sc1" : "=&v"(dst) : "v"(addr) : "memory")

// min over 8 per-wave flags
__device__ __forceinline__ void poll_min8(uint64_t base, unsigned target, int lane) {
    for (;;) {
        unsigned v = 0xFFFFFFFFu;
        if (lane < 8) v = load_flag_sc(base + (uint64_t)lane * 4);
        v = min(v, (unsigned)__shfl_xor((int)v, 1));
        v = min(v, (unsigned)__shfl_xor((int)v, 2));
        v = min(v, (unsigned)__shfl_xor((int)v, 4));
        unsigned seen = (unsigned)__shfl((int)v, 0);
        if (seen >= target) break;
        __builtin_amdgcn_s_sleep(8);
    }
}

#define MFMA16(A, BV, C) __builtin_amdgcn_mfma_f32_16x16x32_f16((A), (BV), (C), 0, 0, 0)
#define MF4(AV, WARR, KT) \
    ac0 = MFMA16(AV, WARR[0][KT], ac0); \
    ac1 = MFMA16(AV, WARR[1][KT], ac1); \
    ac2 = MFMA16(AV, WARR[2][KT], ac2); \
    ac3 = MFMA16(AV, WARR[3][KT], ac3);
#define PF4(AV, KT) \
    px0 = MFMA16(AV, wi[0][KT], px0); \
    px1 = MFMA16(AV, wi[1][KT], px1); \
    px2 = MFMA16(AV, wi[2][KT], px2); \
    px3 = MFMA16(AV, wi[3][KT], px3);

// ---------- one-time conversions (wide grid: 17 blocks, was the serial hotspot) ----------
__global__ __launch_bounds__(256)
void convert_kernel(const float* __restrict__ Wih0, const float* __restrict__ bih0, const float* __restrict__ bhh0,
                    const float* __restrict__ Whh0, const float* __restrict__ Wih1, const float* __restrict__ Whh1,
                    const float* __restrict__ bih1, const float* __restrict__ bhh1,
                    const float* __restrict__ Wl, const float* __restrict__ bl,
                    const float* __restrict__ Wo, const float* __restrict__ bo,
                    __half* __restrict__ W0b, __half* __restrict__ W1b,
                    __half* __restrict__ Whh0h, __half* __restrict__ Whh1h,
                    __half* __restrict__ Wc16, float* __restrict__ b0, float* __restrict__ b1,
                    float* __restrict__ bc)
{
    const int tid = threadIdx.x, bid = blockIdx.x;
    if (bid == 0) {
        for (int i = tid; i < 512; i += 256) { b0[i] = bih0[i] + bhh0[i]; b1[i] = bih1[i] + bhh1[i]; }
        for (int i = tid; i < 512 * 32; i += 256) {
            int r = i >> 5, k = i & 31;
            W0b[i] = __float2half(k < 30 ? Wih0[r * 30 + k] : 0.f);
        }
        if (tid < 64) {
            float a = 0.f;
            if (tid < 63) { a = bo[tid]; for (int m = 0; m < 84; ++m) a += Wo[tid * 84 + m] * bl[m]; }
            bc[tid] = a;
        }
    } else if (bid <= 4) {          // W1b quarters
        const int base = (bid - 1) * 16384;
        for (int i = tid; i < 16384; i += 256) W1b[base + i] = __float2half(Wih1[base + i]);
    } else if (bid <= 8) {          // Whh0h quarters
        const int base = (bid - 5) * 16384;
        for (int i = tid; i < 16384; i += 256) Whh0h[base + i] = __float2half(Whh0[base + i]);
    } else if (bid <= 12) {         // Whh1h quarters
        const int base = (bid - 9) * 16384;
        for (int i = tid; i < 16384; i += 256) Whh1h[base + i] = __float2half(Whh1[base + i]);
    } else {                        // Wc quarters (bid 13..16)
        const int base = (bid - 13) * 2048;
        for (int i = tid; i < 2048; i += 256) {
            int idx = base + i;
            int j = idx >> 7, k = idx & 127;
            float a = 0.f;
            if (j < 63) for (int m = 0; m < 84; ++m) a += Wo[j * 84 + m] * Wl[m * 128 + k];
            Wc16[idx] = __float2half(a);
        }
    }
}

// ---------- fused dual-layer recurrence (R10 structure, verbatim) ----------
// blocks [0,64):   layer-0 rec (20 MFMA/step) + per-16-step full-util xp1 GEMM from LDS h1 ring
// blocks [64,128): layer-1 rec, 8-deep counted-vmcnt xp1 consumption
__global__ __launch_bounds__(512, 2)
void lstm_fused(const float* __restrict__ x,
                const __half* __restrict__ W0b, const __half* __restrict__ Whh0h,
                const __half* __restrict__ W1b, const __half* __restrict__ Whh1h,
                const float* __restrict__ b0, const float* __restrict__ b1,
                __half* __restrict__ xp, __half* __restrict__ h2g,
                unsigned* __restrict__ flags)
{
    const int bid = blockIdx.x;
    const bool producer = bid < 64;
    const int g = bid & 63;           // batch group: batches 4g..4g+3
    const int tid = threadIdx.x;
    const int w = tid >> 6;           // wave -> units 16w..16w+15
    const int lane = tid & 63;
    const int l15 = lane & 15, qg = lane >> 4;
    const int j = w * 16 + l15;       // this lane's unit
    const int r = l15 >> 2;           // A-row batch (duplicated 4x -> LDS broadcast)

    __shared__ __align__(16) char hist[32 * 1280];   // producer h1 ring: [32 steps][4 b x 320B]
    __shared__ __align__(16) char hbuf_s[2][1280];   // consumer h2 tile
    __shared__ __align__(16) __half xl[4][129][32];  // producer x chunk
    char* const hb0 = hbuf_s[0];
    char* const hb1 = hbuf_s[1];

    const int ro0 = r * 320 + 0 * 64 + qg * 16;
    const int ro1 = r * 320 + 1 * 64 + qg * 16;
    const int ro2 = r * 320 + 2 * 64 + qg * 16;
    const int ro3 = r * 320 + 3 * 64 + qg * 16;
    const int wo  = qg * 320 + j * 2;

    for (int i = tid; i < 10240; i += 512) ((unsigned*)hist)[i] = 0;   // h1(-1)=0
    for (int i = tid; i < 320; i += 512) ((unsigned*)hb0)[i] = 0;      // h2(-1)=0

    const uint64_t fb = (uint64_t)(uintptr_t)flags;
    const uint64_t flagbase = fb + (uint64_t)(g * 8) * 4;
    float c = 0.f;

    if (producer) {
        float bias4[4], b14[4];
        f16x8 wx[4], wb[4][4], wi[4][4];
#pragma unroll
        for (int q = 0; q < 4; ++q) {
            bias4[q] = b0[q * 128 + j];
            b14[q]   = b1[q * 128 + j];
            wx[q] = *reinterpret_cast<const f16x8*>(W0b + (size_t)(q * 128 + j) * 32 + qg * 8);
            PINV(wx[q]); PINV(bias4[q]); PINV(b14[q]);
#pragma unroll
            for (int kt = 0; kt < 4; ++kt) {
                wb[q][kt] = *reinterpret_cast<const f16x8*>(Whh0h + (size_t)(q * 128 + j) * 128 + kt * 32 + qg * 8);
                wi[q][kt] = *reinterpret_cast<const f16x8*>(W1b   + (size_t)(q * 128 + j) * 128 + kt * 32 + qg * 8);
                PINV(wb[q][kt]); PINV(wi[q][kt]);
            }
        }
        // zero x padding cols once
        for (int idx = tid; idx < 1024; idx += 512) {
            int b4 = idx >> 8, rest = idx & 255;
            xl[b4][rest >> 1][30 + (rest & 1)] = __float2half(0.f);
        }
        const uint64_t pflag = flagbase + (uint64_t)w * 4;
        const uint64_t xpj = (uint64_t)(uintptr_t)xp + ((uint64_t)(4 * j) << 1);
        const char* xlb = (const char*)xl;
        const int xro = r * 8256 + qg * 16;
        __syncthreads();

        // full-utilization xp1 GEMM for chunk cc2 (16 steps x 4 batches = 64 A-rows)
        auto xp1_gemm = [&](int cc2) {
#pragma unroll
            for (int rt = 0; rt < 4; ++rt) {
                const int row = rt * 16 + l15;
                const char* ap = hist + (((cc2 * 16 + (row >> 2)) & 31) * 1280 + (row & 3) * 320 + qg * 16);
                f16x8 h0_ = *(const f16x8*)(ap + 0);
                f16x8 h1_ = *(const f16x8*)(ap + 64);
                f16x8 h2_ = *(const f16x8*)(ap + 128);
                f16x8 h3_ = *(const f16x8*)(ap + 192);
                f32x4 px0 = (f32x4){b14[0], b14[0], b14[0], b14[0]};
                f32x4 px1 = (f32x4){b14[1], b14[1], b14[1], b14[1]};
                f32x4 px2 = (f32x4){b14[2], b14[2], b14[2], b14[2]};
                f32x4 px3 = (f32x4){b14[3], b14[3], b14[3], b14[3]};
                PF4(h0_, 0) PF4(h1_, 1) PF4(h2_, 2) PF4(h3_, 3)
#pragma unroll
                for (int r4 = 0; r4 < 4; ++r4) {
                    const int ro_ = rt * 16 + qg * 4 + r4;
                    const int tglob = cc2 * 16 + (ro_ >> 2);
                    const int b2 = ro_ & 3;
                    __half2 lo_ = __floats2half2_rn(px0[r4], px1[r4]);
                    __half2 hi_ = __floats2half2_rn(px2[r4], px3[r4]);
                    uint2 pk_;
                    pk_.x = __builtin_bit_cast(unsigned, lo_);
                    pk_.y = __builtin_bit_cast(unsigned, hi_);
                    store_dwordx2_sc(xpj + ((uint64_t)((g * 4 + b2) * T_ + tglob) << 10), pk_);
                }
            }
        };

#define PSTEP(TT) do {                                                          \
        const int t_ = (TT);                                                    \
        const char* rp_ = hist + (((t_ + 31) & 31) * 1280);                     \
        f16x8 a0_ = *(const f16x8*)(rp_ + ro0);                                 \
        f16x8 a1_ = *(const f16x8*)(rp_ + ro1);                                 \
        f16x8 a2_ = *(const f16x8*)(rp_ + ro2);                                 \
        f16x8 a3_ = *(const f16x8*)(rp_ + ro3);                                 \
        f16x8 ax_ = *(const f16x8*)(xlb + (xro + (t_ & 127) * 64));             \
        f32x4 ac0 = (f32x4){bias4[0], 0.f, 0.f, 0.f};                           \
        f32x4 ac1 = (f32x4){bias4[1], 0.f, 0.f, 0.f};                           \
        f32x4 ac2 = (f32x4){bias4[2], 0.f, 0.f, 0.f};                           \
        f32x4 ac3 = (f32x4){bias4[3], 0.f, 0.f, 0.f};                           \
        ac0 = MFMA16(ax_, wx[0], ac0); ac1 = MFMA16(ax_, wx[1], ac1);           \
        ac2 = MFMA16(ax_, wx[2], ac2); ac3 = MFMA16(ax_, wx[3], ac3);           \
        MF4(a0_, wb, 0) MF4(a1_, wb, 1) MF4(a2_, wb, 2) MF4(a3_, wb, 3)         \
        __half hh_ = cell_update(ac0[0], ac1[0], ac2[0], ac3[0], c);            \
        *(__half*)(hist + ((t_ & 31) * 1280 + qg * 320 + j * 2)) = hh_;         \
        if ((t_ & 7) == 7) {                                                    \
            asm volatile("s_waitcnt vmcnt(0)" ::: "memory");                    \
            if (lane == 0) store_flag_sc(pflag, (unsigned)(t_ + 1));            \
        }                                                                       \
        lds_barrier();                                                          \
    } while (0)

        for (int xc = 0; xc < 4; ++xc) {
#pragma unroll 1
            for (int b4 = 0; b4 < 4; ++b4) {
                const float* src = x + ((size_t)(g * 4 + b4) * T_ + xc * 128) * 30;
                for (int idx = tid; idx < 3840; idx += 512) {
                    int tt = idx / 30, ii = idx - tt * 30;
                    xl[b4][tt][ii] = __float2half(src[idx]);
                }
            }
            __syncthreads();
#pragma unroll 1
            for (int sc = 0; sc < 8; ++sc) {
                const int cc = xc * 8 + sc;
                if (cc > 0) xp1_gemm(cc - 1);
                const int tb = cc * 16;
                PSTEP(tb + 0);  PSTEP(tb + 1);  PSTEP(tb + 2);  PSTEP(tb + 3);
                PSTEP(tb + 4);  PSTEP(tb + 5);  PSTEP(tb + 6);  PSTEP(tb + 7);
                PSTEP(tb + 8);  PSTEP(tb + 9);  PSTEP(tb + 10); PSTEP(tb + 11);
                PSTEP(tb + 12); PSTEP(tb + 13); PSTEP(tb + 14); PSTEP(tb + 15);
            }
        }
        xp1_gemm(31);                                   // epilogue chunk
        asm volatile("s_waitcnt vmcnt(0)" ::: "memory");
        if (lane == 0) store_flag_sc(pflag, 999u);
    } else {
        // ================= consumer: layer-1 recurrence =================
        f16x8 wb[4][4];
#pragma unroll
        for (int q = 0; q < 4; ++q)
#pragma unroll
            for (int kt = 0; kt < 4; ++kt) {
                wb[q][kt] = *reinterpret_cast<const f16x8*>(Whh1h + (size_t)(q * 128 + j) * 128 + kt * 32 + qg * 8);
                PINV(wb[q][kt]);
            }
        const int b = g * 4 + qg;
        const uint64_t xpcb = (uint64_t)(uintptr_t)xp + ((uint64_t)(((size_t)b * T_) * 512 + 4 * j) << 1);
        __half* h2p = h2g + ((size_t)b * T_) * H_ + j;
        uint2 xq0, xq1, xq2, xq3, xq4, xq5, xq6, xq7;
        __syncthreads();

// 2 vmem ops/step (1 load + 1 h2 store), 8-deep lead: vmcnt(15) forces L(t) complete at t.
#define CSTEP(TT, XQ) do {                                                      \
        const int t_ = (TT);                                                    \
        const char* rp_ = (t_ & 1) ? hb1 : hb0;                                 \
        char* wp_ = (t_ & 1) ? hb0 : hb1;                                       \
        asm volatile("s_waitcnt vmcnt(15)" ::: "memory");                       \
        __builtin_amdgcn_sched_barrier(0);                                      \
        float2 flo = __half22float2(__builtin_bit_cast(__half2, XQ.x));         \
        float2 fhi = __half22float2(__builtin_bit_cast(__half2, XQ.y));         \
        LOAD8_SC(XQ, xpcb + (uint64_t)(t_ + 8) * 1024);                         \
        f16x8 a0_ = *(const f16x8*)(rp_ + ro0);                                 \
        f16x8 a1_ = *(const f16x8*)(rp_ + ro1);                                 \
        f16x8 a2_ = *(const f16x8*)(rp_ + ro2);                                 \
        f16x8 a3_ = *(const f16x8*)(rp_ + ro3);                                 \
        f32x4 ac0 = (f32x4){flo.x, 0.f, 0.f, 0.f};                              \
        f32x4 ac1 = (f32x4){flo.y, 0.f, 0.f, 0.f};                              \
        f32x4 ac2 = (f32x4){fhi.x, 0.f, 0.f, 0.f};                              \
        f32x4 ac3 = (f32x4){fhi.y, 0.f, 0.f, 0.f};                              \
        MF4(a0_, wb, 0) MF4(a1_, wb, 1) MF4(a2_, wb, 2) MF4(a3_, wb, 3)         \
        __half hh_ = cell_update(ac0[0], ac1[0], ac2[0], ac3[0], c);            \
        *(__half*)(wp_ + wo) = hh_;                                             \
        h2p[(size_t)t_ * H_] = hh_;                                             \
        lds_barrier();                                                          \
    } while (0)

        for (int tg = 0; tg < T_; tg += 16) {
            // xp1 chunk (tg/16)+1 is stored at start of chunk (tg/16)+2, drained by flag tg+40.
            unsigned target = (tg + 40 <= 512) ? (unsigned)(tg + 40) : 999u;
            poll_min8(flagbase, target, lane);
            if (tg == 0) {  // preload 8-deep ring, drain once
                LOAD8_SC(xq0, xpcb + 0 * 1024); LOAD8_SC(xq1, xpcb + 1 * 1024);
                LOAD8_SC(xq2, xpcb + 2 * 1024); LOAD8_SC(xq3, xpcb + 3 * 1024);
                LOAD8_SC(xq4, xpcb + 4 * 1024); LOAD8_SC(xq5, xpcb + 5 * 1024);
                LOAD8_SC(xq6, xpcb + 6 * 1024); LOAD8_SC(xq7, xpcb + 7 * 1024);
                asm volatile("s_waitcnt vmcnt(0)" ::: "memory");
                __builtin_amdgcn_sched_barrier(0);
            }
            CSTEP(tg + 0, xq0);  CSTEP(tg + 1, xq1);  CSTEP(tg + 2, xq2);  CSTEP(tg + 3, xq3);
            CSTEP(tg + 4, xq4);  CSTEP(tg + 5, xq5);  CSTEP(tg + 6, xq6);  CSTEP(tg + 7, xq7);
            CSTEP(tg + 8, xq0);  CSTEP(tg + 9, xq1);  CSTEP(tg + 10, xq2); CSTEP(tg + 11, xq3);
            CSTEP(tg + 12, xq4); CSTEP(tg + 13, xq5); CSTEP(tg + 14, xq6); CSTEP(tg + 15, xq7);
        }
    }
}

// ---------- head: out = h2 @ Wc^T + bc (63 cols, f32) ----------
__global__ __launch_bounds__(256, 4)
void head_kernel(const __half* __restrict__ in, const __half* __restrict__ W16,
                 const float* __restrict__ bias, float* __restrict__ outp)
{
    constexpr int KK = 128;
    const int lane = threadIdx.x & 63;
    const int wn = threadIdx.x >> 6;
    const int rowbase = blockIdx.x * 64;  // ROWT=4
    const int colbase = wn * 16;
    const int l15 = lane & 15, lk = (lane >> 4) * 8;

    float bcol = bias[colbase + l15];
    f32x4 acc[4];
#pragma unroll
    for (int rt = 0; rt < 4; ++rt) acc[rt] = (f32x4){0.f, 0.f, 0.f, 0.f};

#pragma unroll
    for (int kt = 0; kt < 4; ++kt) {
        f16x8 bv = *reinterpret_cast<const f16x8*>(W16 + (size_t)(colbase + l15) * KK + kt * 32 + lk);
#pragma unroll
        for (int rt = 0; rt < 4; ++rt) {
            f16x8 a = *reinterpret_cast<const f16x8*>(in + (size_t)(rowbase + rt * 16 + l15) * KK + kt * 32 + lk);
            acc[rt] = __builtin_amdgcn_mfma_f32_16x16x32_f16(a, bv, acc[rt], 0, 0, 0);
        }
    }
    const int col = colbase + l15;
#pragma unroll
    for (int rt = 0; rt < 4; ++rt)
#pragma unroll
        for (int rr = 0; rr < 4; ++rr) {
            const int row = rowbase + rt * 16 + (lane >> 4) * 4 + rr;
            if (col < 63) outp[(size_t)row * 63 + col] = acc[rt][rr] + bcol;
        }
}

extern "C" void kernel_launch(void* const* d_in, const int* in_sizes, int n_in,
                              void* d_out, int out_size, void* d_ws, size_t ws_size,
                              hipStream_t stream)
{
    const float* x    = (const float*)d_in[0];
    const float* Wih0 = (const float*)d_in[1];
    const float* Whh0 = (const float*)d_in[2];
    const float* bih0 = (const float*)d_in[3];
    const float* bhh0 = (const float*)d_in[4];
    const float* Wih1 = (const float*)d_in[5];
    const float* Whh1 = (const float*)d_in[6];
    const float* bih1 = (const float*)d_in[7];
    const float* bhh1 = (const float*)d_in[8];
    const float* Wl   = (const float*)d_in[9];
    const float* bl   = (const float*)d_in[10];
    const float* Wo   = (const float*)d_in[11];
    const float* bo   = (const float*)d_in[12];
    float* out = (float*)d_out;

    char* ws = (char*)d_ws;
    size_t off = 0;
    auto carve = [&](size_t bytes) { void* p = ws + off; off += (bytes + 255) & ~(size_t)255; return p; };
    __half* xp    = (__half*)carve((size_t)M_ * 512 * 2 + 16384);  // gate stream + prefetch pad
    __half* h2    = (__half*)carve((size_t)M_ * 128 * 2);          // 33.5 MB
    __half* W0b   = (__half*)carve(512 * 32 * 2);
    __half* W1b   = (__half*)carve(512 * 128 * 2);
    __half* Whh0h = (__half*)carve(512 * 128 * 2);
    __half* Whh1h = (__half*)carve(512 * 128 * 2);
    __half* Wc16  = (__half*)carve(64 * 128 * 2);
    float*  b0    = (float*)carve(512 * 4);
    float*  b1    = (float*)carve(512 * 4);
    float*  bc    = (float*)carve(64 * 4);
    unsigned* flags = (unsigned*)carve(2048 * 4);

    hipLaunchKernelGGL(convert_kernel, dim3(17), dim3(256), 0, stream,
                       Wih0, bih0, bhh0, Whh0, Wih1, Whh1, bih1, bhh1, Wl, bl, Wo, bo,
                       W0b, W1b, Whh0h, Whh1h, Wc16, b0, b1, bc);

    hipMemsetAsync(flags, 0, 2048 * 4, stream);  // flags must start at 0 every replay

    hipLaunchKernelGGL(lstm_fused, dim3(128), dim3(512), 0, stream,
                       x, W0b, Whh0h, W1b, Whh1h, b0, b1, xp, h2, flags);

    hipLaunchKernelGGL(head_kernel, dim3(M_ / 64), dim3(256), 0, stream,
                       h2, Wc16, bc, out);
}

// Round 16
// 364.040 us; speedup vs baseline: 2.7887x; 1.0504x over previous
//
#include <hip/hip_runtime.h>
#include <hip/hip_fp16.h>

#define B_ 256
#define T_ 512
#define H_ 128
#define M_ (B_ * T_)  // 131072 rows

typedef _Float16 f16x8 __attribute__((ext_vector_type(8)));
typedef float    f32x4 __attribute__((ext_vector_type(4)));

__device__ __forceinline__ float rcp_f(float a) { return __builtin_amdgcn_rcpf(a); }
__device__ __forceinline__ float sigmoid_f(float a) { return rcp_f(1.f + __expf(-a)); }
__device__ __forceinline__ float tanh_f(float a) { return 1.f - 2.f * rcp_f(__expf(2.f * a) + 1.f); }

// LDS-only barrier: global loads/stores stay in flight (T4: never vmcnt(0) per step).
__device__ __forceinline__ void lds_barrier() {
    asm volatile("s_waitcnt lgkmcnt(0)\n\ts_barrier" ::: "memory");
}

#define PINV(X) asm volatile("" : "+v"(X))

__device__ __forceinline__ __half cell_update(float g0, float g1, float g2, float g3, float& c) {
    float iv = sigmoid_f(g0), fv = sigmoid_f(g1);
    float gv = tanh_f(g2),   ov = sigmoid_f(g3);
    c = fv * c + iv * gv;
    return __float2half(ov * tanh_f(c));
}

// ---- device-visible (cross-XCD via L3) memory ops: sc0 sc1 ----
__device__ __forceinline__ void store_dwordx2_sc(uint64_t addr, uint2 v) {
    asm volatile("global_store_dwordx2 %0, %1, off sc0 sc1" :: "v"(addr), "v"(v) : "memory");
}
__device__ __forceinline__ void store_flag_sc(uint64_t addr, unsigned v) {
    asm volatile("global_store_dword %0, %1, off sc0 sc1" :: "v"(addr), "v"(v) : "memory");
}
__device__ __forceinline__ unsigned load_flag_sc(uint64_t addr) {
    unsigned v;
    asm volatile("global_load_dword %0, %1, off sc0 sc1\n\ts_waitcnt vmcnt(0)"
                 : "=v"(v) : "v"(addr) : "memory");
    return v;
}
#define LOAD8_SC(dst, addr) \
    asm volatile("global_load_dwordx2 %0, %1, off sc0 sc1" : "=&v"(dst) : "v"(addr) : "memory")

// min over 8 per-wave flags
__device__ __forceinline__ void poll_min8(uint64_t base, unsigned target, int lane) {
    for (;;) {
        unsigned v = 0xFFFFFFFFu;
        if (lane < 8) v = load_flag_sc(base + (uint64_t)lane * 4);
        v = min(v, (unsigned)__shfl_xor((int)v, 1));
        v = min(v, (unsigned)__shfl_xor((int)v, 2));
        v = min(v, (unsigned)__shfl_xor((int)v, 4));
        unsigned seen = (unsigned)__shfl((int)v, 0);
        if (seen >= target) break;
        __builtin_amdgcn_s_sleep(8);
    }
}

#define MFMA16(A, BV, C) __builtin_amdgcn_mfma_f32_16x16x32_f16((A), (BV), (C), 0, 0, 0)
#define MF4(AV, WARR, KT) \
    ac0 = MFMA16(AV, WARR[0][KT], ac0); \
    ac1 = MFMA16(AV, WARR[1][KT], ac1); \
    ac2 = MFMA16(AV, WARR[2][KT], ac2); \
    ac3 = MFMA16(AV, WARR[3][KT], ac3);
#define PF4(AV, KT) \
    px0 = MFMA16(AV, wi[0][KT], px0); \
    px1 = MFMA16(AV, wi[1][KT], px1); \
    px2 = MFMA16(AV, wi[2][KT], px2); \
    px3 = MFMA16(AV, wi[3][KT], px3);

// ---------- one-time conversions (17 blocks) ----------
__global__ __launch_bounds__(256)
void convert_kernel(const float* __restrict__ Wih0, const float* __restrict__ bih0, const float* __restrict__ bhh0,
                    const float* __restrict__ Whh0, const float* __restrict__ Wih1, const float* __restrict__ Whh1,
                    const float* __restrict__ bih1, const float* __restrict__ bhh1,
                    const float* __restrict__ Wl, const float* __restrict__ bl,
                    const float* __restrict__ Wo, const float* __restrict__ bo,
                    __half* __restrict__ W0b, __half* __restrict__ W1b,
                    __half* __restrict__ Whh0h, __half* __restrict__ Whh1h,
                    __half* __restrict__ Wc16, float* __restrict__ b0, float* __restrict__ b1,
                    float* __restrict__ bc)
{
    const int tid = threadIdx.x, bid = blockIdx.x;
    if (bid == 0) {
        for (int i = tid; i < 512; i += 256) { b0[i] = bih0[i] + bhh0[i]; b1[i] = bih1[i] + bhh1[i]; }
        for (int i = tid; i < 512 * 32; i += 256) {
            int r = i >> 5, k = i & 31;
            W0b[i] = __float2half(k < 30 ? Wih0[r * 30 + k] : 0.f);
        }
        if (tid < 64) {
            float a = 0.f;
            if (tid < 63) { a = bo[tid]; for (int m = 0; m < 84; ++m) a += Wo[tid * 84 + m] * bl[m]; }
            bc[tid] = a;
        }
    } else if (bid <= 4) {
        const int base = (bid - 1) * 16384;
        for (int i = tid; i < 16384; i += 256) W1b[base + i] = __float2half(Wih1[base + i]);
    } else if (bid <= 8) {
        const int base = (bid - 5) * 16384;
        for (int i = tid; i < 16384; i += 256) Whh0h[base + i] = __float2half(Whh0[base + i]);
    } else if (bid <= 12) {
        const int base = (bid - 9) * 16384;
        for (int i = tid; i < 16384; i += 256) Whh1h[base + i] = __float2half(Whh1[base + i]);
    } else {
        const int base = (bid - 13) * 2048;
        for (int i = tid; i < 2048; i += 256) {
            int idx = base + i;
            int j = idx >> 7, k = idx & 127;
            float a = 0.f;
            if (j < 63) for (int m = 0; m < 84; ++m) a += Wo[j * 84 + m] * Wl[m * 128 + k];
            Wc16[idx] = __float2half(a);
        }
    }
}

// ---------- fused dual-layer recurrence: 2 batches/group, 256 blocks -> 2 blocks/CU ----------
// blocks [0,128):   producer, group g=bid, batches 2g..2g+1
// blocks [128,256): consumer, group g=bid-128
// Lanes qg>=2 duplicate qg-2's batch (MFMA rows already duplicated); global stores gated.
// 2 co-resident blocks per CU interleave independently -> stalls of one fill with issue of the other.
__global__ __launch_bounds__(512, 2)
void lstm_fused(const float* __restrict__ x,
                const __half* __restrict__ W0b, const __half* __restrict__ Whh0h,
                const __half* __restrict__ W1b, const __half* __restrict__ Whh1h,
                const float* __restrict__ b0, const float* __restrict__ b1,
                __half* __restrict__ xp, __half* __restrict__ h2g,
                unsigned* __restrict__ flags)
{
    const int bid = blockIdx.x;
    const bool producer = bid < 128;
    const int g = producer ? bid : bid - 128;   // group: batches 2g, 2g+1
    const int tid = threadIdx.x;
    const int w = tid >> 6;
    const int lane = tid & 63;
    const int l15 = lane & 15, qg = lane >> 4;
    const int j = w * 16 + l15;
    const int r = l15 >> 2;          // A-row group (batch = r&1, 8x duplicated)

    __shared__ __align__(16) char hist[32 * 1280];   // h1 ring [32 steps][4 rows x 320B] (rows 2,3 dup 0,1)
    __shared__ __align__(16) char hbuf_s[2][1280];
    __shared__ __align__(16) __half xl[2][129][32];  // 2 batches only
    char* const hb0 = hbuf_s[0];
    char* const hb1 = hbuf_s[1];

    const int ro0 = r * 320 + 0 * 64 + qg * 16;
    const int ro1 = r * 320 + 1 * 64 + qg * 16;
    const int ro2 = r * 320 + 2 * 64 + qg * 16;
    const int ro3 = r * 320 + 3 * 64 + qg * 16;
    const int wo  = qg * 320 + j * 2;

    for (int i = tid; i < 10240; i += 512) ((unsigned*)hist)[i] = 0;
    for (int i = tid; i < 320; i += 512) ((unsigned*)hb0)[i] = 0;

    const uint64_t fb = (uint64_t)(uintptr_t)flags;
    const uint64_t flagbase = fb + (uint64_t)(g * 8) * 4;
    float c = 0.f;

    if (producer) {
        float bias4[4], b14[4];
        f16x8 wx[4], wb[4][4], wi[4][4];
#pragma unroll
        for (int q = 0; q < 4; ++q) {
            bias4[q] = b0[q * 128 + j];
            b14[q]   = b1[q * 128 + j];
            wx[q] = *reinterpret_cast<const f16x8*>(W0b + (size_t)(q * 128 + j) * 32 + qg * 8);
            PINV(wx[q]); PINV(bias4[q]); PINV(b14[q]);
#pragma unroll
            for (int kt = 0; kt < 4; ++kt) {
                wb[q][kt] = *reinterpret_cast<const f16x8*>(Whh0h + (size_t)(q * 128 + j) * 128 + kt * 32 + qg * 8);
                wi[q][kt] = *reinterpret_cast<const f16x8*>(W1b   + (size_t)(q * 128 + j) * 128 + kt * 32 + qg * 8);
                PINV(wb[q][kt]); PINV(wi[q][kt]);
            }
        }
        for (int idx = tid; idx < 512; idx += 512) {
            int b4 = idx >> 8, rest = idx & 255;
            xl[b4][rest >> 1][30 + (rest & 1)] = __float2half(0.f);
        }
        if (tid < 512) {  // zero both batches' pad cols (2 x 256 entries)
            int idx = tid;
            if (idx < 512) {
                int b4 = idx >> 8, rest = idx & 255;
                xl[b4][rest >> 1][30 + (rest & 1)] = __float2half(0.f);
            }
        }
        const uint64_t pflag = flagbase + (uint64_t)w * 4;
        const uint64_t xpj = (uint64_t)(uintptr_t)xp + ((uint64_t)(4 * j) << 1);
        const char* xlb = (const char*)xl;
        const int xro = (r & 1) * 8256 + qg * 16;
        __syncthreads();

        // xp1 GEMM for chunk cc2: 64 A-rows (16 steps x 4 dup-rows); store only b2<2
        auto xp1_gemm = [&](int cc2) {
#pragma unroll
            for (int rt = 0; rt < 4; ++rt) {
                const int row = rt * 16 + l15;
                const char* ap = hist + (((cc2 * 16 + (row >> 2)) & 31) * 1280 + (row & 3) * 320 + qg * 16);
                f16x8 h0_ = *(const f16x8*)(ap + 0);
                f16x8 h1_ = *(const f16x8*)(ap + 64);
                f16x8 h2_ = *(const f16x8*)(ap + 128);
                f16x8 h3_ = *(const f16x8*)(ap + 192);
                f32x4 px0 = (f32x4){b14[0], b14[0], b14[0], b14[0]};
                f32x4 px1 = (f32x4){b14[1], b14[1], b14[1], b14[1]};
                f32x4 px2 = (f32x4){b14[2], b14[2], b14[2], b14[2]};
                f32x4 px3 = (f32x4){b14[3], b14[3], b14[3], b14[3]};
                PF4(h0_, 0) PF4(h1_, 1) PF4(h2_, 2) PF4(h3_, 3)
#pragma unroll
                for (int r4 = 0; r4 < 4; ++r4) {
                    const int ro_ = rt * 16 + qg * 4 + r4;
                    const int tglob = cc2 * 16 + (ro_ >> 2);
                    const int b2 = ro_ & 3;
                    if (b2 < 2) {
                        __half2 lo_ = __floats2half2_rn(px0[r4], px1[r4]);
                        __half2 hi_ = __floats2half2_rn(px2[r4], px3[r4]);
                        uint2 pk_;
                        pk_.x = __builtin_bit_cast(unsigned, lo_);
                        pk_.y = __builtin_bit_cast(unsigned, hi_);
                        store_dwordx2_sc(xpj + ((uint64_t)((g * 2 + b2) * T_ + tglob) << 10), pk_);
                    }
                }
            }
        };

#define PSTEP(TT) do {                                                          \
        const int t_ = (TT);                                                    \
        const char* rp_ = hist + (((t_ + 31) & 31) * 1280);                     \
        f16x8 a0_ = *(const f16x8*)(rp_ + ro0);                                 \
        f16x8 a1_ = *(const f16x8*)(rp_ + ro1);                                 \
        f16x8 a2_ = *(const f16x8*)(rp_ + ro2);                                 \
        f16x8 a3_ = *(const f16x8*)(rp_ + ro3);                                 \
        f16x8 ax_ = *(const f16x8*)(xlb + (xro + (t_ & 127) * 64));             \
        f32x4 ac0 = (f32x4){bias4[0], 0.f, 0.f, 0.f};                           \
        f32x4 ac1 = (f32x4){bias4[1], 0.f, 0.f, 0.f};                           \
        f32x4 ac2 = (f32x4){bias4[2], 0.f, 0.f, 0.f};                           \
        f32x4 ac3 = (f32x4){bias4[3], 0.f, 0.f, 0.f};                           \
        ac0 = MFMA16(ax_, wx[0], ac0); ac1 = MFMA16(ax_, wx[1], ac1);           \
        ac2 = MFMA16(ax_, wx[2], ac2); ac3 = MFMA16(ax_, wx[3], ac3);           \
        MF4(a0_, wb, 0) MF4(a1_, wb, 1) MF4(a2_, wb, 2) MF4(a3_, wb, 3)         \
        __half hh_ = cell_update(ac0[0], ac1[0], ac2[0], ac3[0], c);            \
        *(__half*)(hist + ((t_ & 31) * 1280 + qg * 320 + j * 2)) = hh_;         \
        if ((t_ & 7) == 7) {                                                    \
            asm volatile("s_waitcnt vmcnt(0)" ::: "memory");                    \
            if (lane == 0) store_flag_sc(pflag, (unsigned)(t_ + 1));            \
        }                                                                       \
        lds_barrier();                                                          \
    } while (0)

        for (int xc = 0; xc < 4; ++xc) {
#pragma unroll 1
            for (int b4 = 0; b4 < 2; ++b4) {
                const float* src = x + ((size_t)(g * 2 + b4) * T_ + xc * 128) * 30;
                for (int idx = tid; idx < 3840; idx += 512) {
                    int tt = idx / 30, ii = idx - tt * 30;
                    xl[b4][tt][ii] = __float2half(src[idx]);
                }
            }
            __syncthreads();
#pragma unroll 1
            for (int sc = 0; sc < 8; ++sc) {
                const int cc = xc * 8 + sc;
                if (cc > 0) xp1_gemm(cc - 1);
                const int tb = cc * 16;
                PSTEP(tb + 0);  PSTEP(tb + 1);  PSTEP(tb + 2);  PSTEP(tb + 3);
                PSTEP(tb + 4);  PSTEP(tb + 5);  PSTEP(tb + 6);  PSTEP(tb + 7);
                PSTEP(tb + 8);  PSTEP(tb + 9);  PSTEP(tb + 10); PSTEP(tb + 11);
                PSTEP(tb + 12); PSTEP(tb + 13); PSTEP(tb + 14); PSTEP(tb + 15);
            }
        }
        xp1_gemm(31);
        asm volatile("s_waitcnt vmcnt(0)" ::: "memory");
        if (lane == 0) store_flag_sc(pflag, 999u);
    } else {
        // ================= consumer: layer-1 recurrence =================
        f16x8 wb[4][4];
#pragma unroll
        for (int q = 0; q < 4; ++q)
#pragma unroll
            for (int kt = 0; kt < 4; ++kt) {
                wb[q][kt] = *reinterpret_cast<const f16x8*>(Whh1h + (size_t)(q * 128 + j) * 128 + kt * 32 + qg * 8);
                PINV(wb[q][kt]);
            }
        const int b = g * 2 + (qg & 1);          // duplicate lanes qg 2-3
        const bool wrl = qg < 2;                 // gate global h2 stores
        const uint64_t xpcb = (uint64_t)(uintptr_t)xp + ((uint64_t)(((size_t)b * T_) * 512 + 4 * j) << 1);
        __half* h2p = h2g + ((size_t)b * T_) * H_ + j;
        uint2 xq0, xq1, xq2, xq3, xq4, xq5, xq6, xq7;
        __syncthreads();

#define CSTEP(TT, XQ) do {                                                      \
        const int t_ = (TT);                                                    \
        const char* rp_ = (t_ & 1) ? hb1 : hb0;                                 \
        char* wp_ = (t_ & 1) ? hb0 : hb1;                                       \
        asm volatile("s_waitcnt vmcnt(15)" ::: "memory");                       \
        __builtin_amdgcn_sched_barrier(0);                                      \
        float2 flo = __half22float2(__builtin_bit_cast(__half2, XQ.x));         \
        float2 fhi = __half22float2(__builtin_bit_cast(__half2, XQ.y));         \
        LOAD8_SC(XQ, xpcb + (uint64_t)(t_ + 8) * 1024);                         \
        f16x8 a0_ = *(const f16x8*)(rp_ + ro0);                                 \
        f16x8 a1_ = *(const f16x8*)(rp_ + ro1);                                 \
        f16x8 a2_ = *(const f16x8*)(rp_ + ro2);                                 \
        f16x8 a3_ = *(const f16x8*)(rp_ + ro3);                                 \
        f32x4 ac0 = (f32x4){flo.x, 0.f, 0.f, 0.f};                              \
        f32x4 ac1 = (f32x4){flo.y, 0.f, 0.f, 0.f};                              \
        f32x4 ac2 = (f32x4){fhi.x, 0.f, 0.f, 0.f};                              \
        f32x4 ac3 = (f32x4){fhi.y, 0.f, 0.f, 0.f};                              \
        MF4(a0_, wb, 0) MF4(a1_, wb, 1) MF4(a2_, wb, 2) MF4(a3_, wb, 3)         \
        __half hh_ = cell_update(ac0[0], ac1[0], ac2[0], ac3[0], c);            \
        *(__half*)(wp_ + wo) = hh_;                                             \
        if (wrl) h2p[(size_t)t_ * H_] = hh_;                                    \
        lds_barrier();                                                          \
    } while (0)

        for (int tg = 0; tg < T_; tg += 16) {
            unsigned target = (tg + 40 <= 512) ? (unsigned)(tg + 40) : 999u;
            poll_min8(flagbase, target, lane);
            if (tg == 0) {
                LOAD8_SC(xq0, xpcb + 0 * 1024); LOAD8_SC(xq1, xpcb + 1 * 1024);
                LOAD8_SC(xq2, xpcb + 2 * 1024); LOAD8_SC(xq3, xpcb + 3 * 1024);
                LOAD8_SC(xq4, xpcb + 4 * 1024); LOAD8_SC(xq5, xpcb + 5 * 1024);
                LOAD8_SC(xq6, xpcb + 6 * 1024); LOAD8_SC(xq7, xpcb + 7 * 1024);
                asm volatile("s_waitcnt vmcnt(0)" ::: "memory");
                __builtin_amdgcn_sched_barrier(0);
            }
            CSTEP(tg + 0, xq0);  CSTEP(tg + 1, xq1);  CSTEP(tg + 2, xq2);  CSTEP(tg + 3, xq3);
            CSTEP(tg + 4, xq4);  CSTEP(tg + 5, xq5);  CSTEP(tg + 6, xq6);  CSTEP(tg + 7, xq7);
            CSTEP(tg + 8, xq0);  CSTEP(tg + 9, xq1);  CSTEP(tg + 10, xq2); CSTEP(tg + 11, xq3);
            CSTEP(tg + 12, xq4); CSTEP(tg + 13, xq5); CSTEP(tg + 14, xq6); CSTEP(tg + 15, xq7);
        }
    }
}

// ---------- head: out = h2 @ Wc^T + bc (63 cols, f32) ----------
__global__ __launch_bounds__(256, 4)
void head_kernel(const __half* __restrict__ in, const __half* __restrict__ W16,
                 const float* __restrict__ bias, float* __restrict__ outp)
{
    constexpr int KK = 128;
    const int lane = threadIdx.x & 63;
    const int wn = threadIdx.x >> 6;
    const int rowbase = blockIdx.x * 64;
    const int colbase = wn * 16;
    const int l15 = lane & 15, lk = (lane >> 4) * 8;

    float bcol = bias[colbase + l15];
    f32x4 acc[4];
#pragma unroll
    for (int rt = 0; rt < 4; ++rt) acc[rt] = (f32x4){0.f, 0.f, 0.f, 0.f};

#pragma unroll
    for (int kt = 0; kt < 4; ++kt) {
        f16x8 bv = *reinterpret_cast<const f16x8*>(W16 + (size_t)(colbase + l15) * KK + kt * 32 + lk);
#pragma unroll
        for (int rt = 0; rt < 4; ++rt) {
            f16x8 a = *reinterpret_cast<const f16x8*>(in + (size_t)(rowbase + rt * 16 + l15) * KK + kt * 32 + lk);
            acc[rt] = __builtin_amdgcn_mfma_f32_16x16x32_f16(a, bv, acc[rt], 0, 0, 0);
        }
    }
    const int col = colbase + l15;
#pragma unroll
    for (int rt = 0; rt < 4; ++rt)
#pragma unroll
        for (int rr = 0; rr < 4; ++rr) {
            const int row = rowbase + rt * 16 + (lane >> 4) * 4 + rr;
            if (col < 63) outp[(size_t)row * 63 + col] = acc[rt][rr] + bcol;
        }
}

extern "C" void kernel_launch(void* const* d_in, const int* in_sizes, int n_in,
                              void* d_out, int out_size, void* d_ws, size_t ws_size,
                              hipStream_t stream)
{
    const float* x    = (const float*)d_in[0];
    const float* Wih0 = (const float*)d_in[1];
    const float* Whh0 = (const float*)d_in[2];
    const float* bih0 = (const float*)d_in[3];
    const float* bhh0 = (const float*)d_in[4];
    const float* Wih1 = (const float*)d_in[5];
    const float* Whh1 = (const float*)d_in[6];
    const float* bih1 = (const float*)d_in[7];
    const float* bhh1 = (const float*)d_in[8];
    const float* Wl   = (const float*)d_in[9];
    const float* bl   = (const float*)d_in[10];
    const float* Wo   = (const float*)d_in[11];
    const float* bo   = (const float*)d_in[12];
    float* out = (float*)d_out;

    char* ws = (char*)d_ws;
    size_t off = 0;
    auto carve = [&](size_t bytes) { void* p = ws + off; off += (bytes + 255) & ~(size_t)255; return p; };
    __half* xp    = (__half*)carve((size_t)M_ * 512 * 2 + 16384);  // gate stream + prefetch pad
    __half* h2    = (__half*)carve((size_t)M_ * 128 * 2);          // 33.5 MB
    __half* W0b   = (__half*)carve(512 * 32 * 2);
    __half* W1b   = (__half*)carve(512 * 128 * 2);
    __half* Whh0h = (__half*)carve(512 * 128 * 2);
    __half* Whh1h = (__half*)carve(512 * 128 * 2);
    __half* Wc16  = (__half*)carve(64 * 128 * 2);
    float*  b0    = (float*)carve(512 * 4);
    float*  b1    = (float*)carve(512 * 4);
    float*  bc    = (float*)carve(64 * 4);
    unsigned* flags = (unsigned*)carve(2048 * 4);

    hipLaunchKernelGGL(convert_kernel, dim3(17), dim3(256), 0, stream,
                       Wih0, bih0, bhh0, Whh0, Wih1, Whh1, bih1, bhh1, Wl, bl, Wo, bo,
                       W0b, W1b, Whh0h, Whh1h, Wc16, b0, b1, bc);

    hipMemsetAsync(flags, 0, 2048 * 4, stream);  // flags must start at 0 every replay

    hipLaunchKernelGGL(lstm_fused, dim3(256), dim3(512), 0, stream,
                       x, W0b, Whh0h, W1b, Whh1h, b0, b1, xp, h2, flags);

    hipLaunchKernelGGL(head_kernel, dim3(M_ / 64), dim3(256), 0, stream,
                       h2, Wc16, bc, out);
}

// Round 17
// 356.632 us; speedup vs baseline: 2.8466x; 1.0208x over previous
//
#include <hip/hip_runtime.h>
#include <hip/hip_fp16.h>

#define B_ 256
#define T_ 512
#define H_ 128
#define M_ (B_ * T_)  // 131072 rows

typedef _Float16 f16x8 __attribute__((ext_vector_type(8)));
typedef float    f32x4 __attribute__((ext_vector_type(4)));

__device__ __forceinline__ float rcp_f(float a) { return __builtin_amdgcn_rcpf(a); }
__device__ __forceinline__ float sigmoid_f(float a) { return rcp_f(1.f + __expf(-a)); }
__device__ __forceinline__ float tanh_f(float a) { return 1.f - 2.f * rcp_f(__expf(2.f * a) + 1.f); }

// LDS-only barrier: global loads/stores stay in flight (T4: never vmcnt(0) per step).
__device__ __forceinline__ void lds_barrier() {
    asm volatile("s_waitcnt lgkmcnt(0)\n\ts_barrier" ::: "memory");
}

#define PINV(X) asm volatile("" : "+v"(X))

__device__ __forceinline__ __half cell_update(float g0, float g1, float g2, float g3, float& c) {
    float iv = sigmoid_f(g0), fv = sigmoid_f(g1);
    float gv = tanh_f(g2),   ov = sigmoid_f(g3);
    c = fv * c + iv * gv;
    return __float2half(ov * tanh_f(c));
}

// ---- device-visible (cross-XCD via L3) memory ops: sc0 sc1 ----
__device__ __forceinline__ void store_dwordx2_sc(uint64_t addr, uint2 v) {
    asm volatile("global_store_dwordx2 %0, %1, off sc0 sc1" :: "v"(addr), "v"(v) : "memory");
}
__device__ __forceinline__ void store_flag_sc(uint64_t addr, unsigned v) {
    asm volatile("global_store_dword %0, %1, off sc0 sc1" :: "v"(addr), "v"(v) : "memory");
}
__device__ __forceinline__ unsigned load_flag_sc(uint64_t addr) {
    unsigned v;
    asm volatile("global_load_dword %0, %1, off sc0 sc1\n\ts_waitcnt vmcnt(0)"
                 : "=v"(v) : "v"(addr) : "memory");
    return v;
}
#define LOAD8_SC(dst, addr) \
    asm volatile("global_load_dwordx2 %0, %1, off sc0 sc1" : "=&v"(dst) : "v"(addr) : "memory")

// min over 8 per-wave flags
__device__ __forceinline__ void poll_min8(uint64_t base, unsigned target, int lane) {
    for (;;) {
        unsigned v = 0xFFFFFFFFu;
        if (lane < 8) v = load_flag_sc(base + (uint64_t)lane * 4);
        v = min(v, (unsigned)__shfl_xor((int)v, 1));
        v = min(v, (unsigned)__shfl_xor((int)v, 2));
        v = min(v, (unsigned)__shfl_xor((int)v, 4));
        unsigned seen = (unsigned)__shfl((int)v, 0);
        if (seen >= target) break;
        __builtin_amdgcn_s_sleep(8);
    }
}

#define MFMA16(A, BV, C) __builtin_amdgcn_mfma_f32_16x16x32_f16((A), (BV), (C), 0, 0, 0)
#define MF4(AV, WARR, KT) \
    ac0 = MFMA16(AV, WARR[0][KT], ac0); \
    ac1 = MFMA16(AV, WARR[1][KT], ac1); \
    ac2 = MFMA16(AV, WARR[2][KT], ac2); \
    ac3 = MFMA16(AV, WARR[3][KT], ac3);
#define PF4(AV, KT) \
    px0 = MFMA16(AV, wi[0][KT], px0); \
    px1 = MFMA16(AV, wi[1][KT], px1); \
    px2 = MFMA16(AV, wi[2][KT], px2); \
    px3 = MFMA16(AV, wi[3][KT], px3);

// ---------- one-time conversions (17 blocks) ----------
__global__ __launch_bounds__(256)
void convert_kernel(const float* __restrict__ Wih0, const float* __restrict__ bih0, const float* __restrict__ bhh0,
                    const float* __restrict__ Whh0, const float* __restrict__ Wih1, const float* __restrict__ Whh1,
                    const float* __restrict__ bih1, const float* __restrict__ bhh1,
                    const float* __restrict__ Wl, const float* __restrict__ bl,
                    const float* __restrict__ Wo, const float* __restrict__ bo,
                    __half* __restrict__ W0b, __half* __restrict__ W1b,
                    __half* __restrict__ Whh0h, __half* __restrict__ Whh1h,
                    __half* __restrict__ Wc16, float* __restrict__ b0, float* __restrict__ b1,
                    float* __restrict__ bc)
{
    const int tid = threadIdx.x, bid = blockIdx.x;
    if (bid == 0) {
        for (int i = tid; i < 512; i += 256) { b0[i] = bih0[i] + bhh0[i]; b1[i] = bih1[i] + bhh1[i]; }
        for (int i = tid; i < 512 * 32; i += 256) {
            int r = i >> 5, k = i & 31;
            W0b[i] = __float2half(k < 30 ? Wih0[r * 30 + k] : 0.f);
        }
        if (tid < 64) {
            float a = 0.f;
            if (tid < 63) { a = bo[tid]; for (int m = 0; m < 84; ++m) a += Wo[tid * 84 + m] * bl[m]; }
            bc[tid] = a;
        }
    } else if (bid <= 4) {
        const int base = (bid - 1) * 16384;
        for (int i = tid; i < 16384; i += 256) W1b[base + i] = __float2half(Wih1[base + i]);
    } else if (bid <= 8) {
        const int base = (bid - 5) * 16384;
        for (int i = tid; i < 16384; i += 256) Whh0h[base + i] = __float2half(Whh0[base + i]);
    } else if (bid <= 12) {
        const int base = (bid - 9) * 16384;
        for (int i = tid; i < 16384; i += 256) Whh1h[base + i] = __float2half(Whh1[base + i]);
    } else {
        const int base = (bid - 13) * 2048;
        for (int i = tid; i < 2048; i += 256) {
            int idx = base + i;
            int j = idx >> 7, k = idx & 127;
            float a = 0.f;
            if (j < 63) for (int m = 0; m < 84; ++m) a += Wo[j * 84 + m] * Wl[m * 128 + k];
            Wc16[idx] = __float2half(a);
        }
    }
}

// ---------- fused dual-layer recurrence: 2 batches/group, 256 blocks, 2 blocks/CU ----------
// Producer MFMA diet vs R16: xp0 bursts (2-step chunks -> gb0) and packed xp1 gemm (32 real rows)
// cut 24 -> 20 MFMA/wave/step. h1 ring shrunk to 16 steps so LDS stays 2-blocks/CU.
__global__ __launch_bounds__(512, 2)
void lstm_fused(const float* __restrict__ x,
                const __half* __restrict__ W0b, const __half* __restrict__ Whh0h,
                const __half* __restrict__ W1b, const __half* __restrict__ Whh1h,
                const float* __restrict__ b0, const float* __restrict__ b1,
                __half* __restrict__ xp, __half* __restrict__ h2g,
                unsigned* __restrict__ flags)
{
    const int bid = blockIdx.x;
    const bool producer = bid < 128;
    const int g = producer ? bid : bid - 128;   // group: batches 2g, 2g+1
    const int tid = threadIdx.x;
    const int w = tid >> 6;
    const int lane = tid & 63;
    const int l15 = lane & 15, qg = lane >> 4;
    const int j = w * 16 + l15;
    const int r = l15 >> 2;          // A-row group (batch = r&1, duplicated)

    __shared__ __align__(16) char hist[16 * 1280];   // h1 ring [16 steps][4 rows x 320B]
    __shared__ __align__(16) char hbuf_s[2][1280];
    __shared__ __align__(16) __half xl[2][129][32];  // x chunk, 2 batches x 128 steps
    __shared__ __align__(16) char gb0[2 * 8 * 1040]; // xp0 gates: 2 x (2 steps x 4 rows) x 1040B
    char* const hb0 = hbuf_s[0];
    char* const hb1 = hbuf_s[1];

    const int ro0 = r * 320 + 0 * 64 + qg * 16;
    const int ro1 = r * 320 + 1 * 64 + qg * 16;
    const int ro2 = r * 320 + 2 * 64 + qg * 16;
    const int ro3 = r * 320 + 3 * 64 + qg * 16;
    const int wo  = qg * 320 + j * 2;

    for (int i = tid; i < 5120; i += 512) ((unsigned*)hist)[i] = 0;
    for (int i = tid; i < 320; i += 512) ((unsigned*)hb0)[i] = 0;

    const uint64_t fb = (uint64_t)(uintptr_t)flags;
    const uint64_t flagbase = fb + (uint64_t)(g * 8) * 4;
    float c = 0.f;

    if (producer) {
        float bias4[4], b14[4];
        f16x8 wx[4], wb[4][4], wi[4][4];
#pragma unroll
        for (int q = 0; q < 4; ++q) {
            bias4[q] = b0[q * 128 + j];
            b14[q]   = b1[q * 128 + j];
            wx[q] = *reinterpret_cast<const f16x8*>(W0b + (size_t)(q * 128 + j) * 32 + qg * 8);
            PINV(wx[q]); PINV(bias4[q]); PINV(b14[q]);
#pragma unroll
            for (int kt = 0; kt < 4; ++kt) {
                wb[q][kt] = *reinterpret_cast<const f16x8*>(Whh0h + (size_t)(q * 128 + j) * 128 + kt * 32 + qg * 8);
                wi[q][kt] = *reinterpret_cast<const f16x8*>(W1b   + (size_t)(q * 128 + j) * 128 + kt * 32 + qg * 8);
                PINV(wb[q][kt]); PINV(wi[q][kt]);
            }
        }
        // zero x padding cols once (2 batches x 128 steps x cols 30,31)
        for (int idx = tid; idx < 512; idx += 512) {
            int b4 = idx >> 8, rest = idx & 255;
            xl[b4][rest >> 1][30 + (rest & 1)] = __float2half(0.f);
        }
        const uint64_t pflag = flagbase + (uint64_t)w * 4;
        const uint64_t xpj = (uint64_t)(uintptr_t)xp + ((uint64_t)(4 * j) << 1);
        const char* xlb = (const char*)xl;
        __syncthreads();

        // xp1 GEMM for 16-step chunk cc2: 32 PACKED rows (row = s*2 + b), all stores useful
        auto xp1_gemm = [&](int cc2) {
#pragma unroll
            for (int rt = 0; rt < 2; ++rt) {
                const int row = rt * 16 + l15;
                const int s_ = row >> 1, b2_ = row & 1;
                const char* ap = hist + (((cc2 * 16 + s_) & 15) * 1280 + b2_ * 320 + qg * 16);
                f16x8 h0_ = *(const f16x8*)(ap + 0);
                f16x8 h1_ = *(const f16x8*)(ap + 64);
                f16x8 h2_ = *(const f16x8*)(ap + 128);
                f16x8 h3_ = *(const f16x8*)(ap + 192);
                f32x4 px0 = (f32x4){b14[0], b14[0], b14[0], b14[0]};
                f32x4 px1 = (f32x4){b14[1], b14[1], b14[1], b14[1]};
                f32x4 px2 = (f32x4){b14[2], b14[2], b14[2], b14[2]};
                f32x4 px3 = (f32x4){b14[3], b14[3], b14[3], b14[3]};
                PF4(h0_, 0) PF4(h1_, 1) PF4(h2_, 2) PF4(h3_, 3)
#pragma unroll
                for (int r4 = 0; r4 < 4; ++r4) {
                    const int ro_ = rt * 16 + qg * 4 + r4;
                    const int s2 = ro_ >> 1, b2 = ro_ & 1;
                    __half2 lo_ = __floats2half2_rn(px0[r4], px1[r4]);
                    __half2 hi_ = __floats2half2_rn(px2[r4], px3[r4]);
                    uint2 pk_;
                    pk_.x = __builtin_bit_cast(unsigned, lo_);
                    pk_.y = __builtin_bit_cast(unsigned, hi_);
                    store_dwordx2_sc(xpj + ((uint64_t)((g * 2 + b2) * T_ + cc2 * 16 + s2) << 10), pk_);
                }
            }
        };

// xp0 burst for 2-step chunk CC (steps 2CC, 2CC+1): 4 MFMA, gates -> gb0[CC&1]
// A-row m: s=(m>>2)&1, b=m&1. Writer lane qg stores r4 0,1 to gb row (qg&1)*4+(qg>>1)*2+r4.
#define XP0B(CC) do {                                                           \
        const int sl_ = (l15 >> 2) & 1, bb_ = l15 & 1;                          \
        f16x8 ax_ = *(const f16x8*)(xlb + bb_ * 8256 + ((((CC) * 2 + sl_) & 127) * 64) + qg * 16); \
        f32x4 px0 = (f32x4){bias4[0], bias4[0], bias4[0], bias4[0]};            \
        f32x4 px1 = (f32x4){bias4[1], bias4[1], bias4[1], bias4[1]};            \
        f32x4 px2 = (f32x4){bias4[2], bias4[2], bias4[2], bias4[2]};            \
        f32x4 px3 = (f32x4){bias4[3], bias4[3], bias4[3], bias4[3]};            \
        px0 = MFMA16(ax_, wx[0], px0); px1 = MFMA16(ax_, wx[1], px1);           \
        px2 = MFMA16(ax_, wx[2], px2); px3 = MFMA16(ax_, wx[3], px3);           \
        char* gd_ = gb0 + ((CC) & 1) * 8320 + 8 * j;                            \
        _Pragma("unroll")                                                       \
        for (int r4 = 0; r4 < 2; ++r4) {                                        \
            const int grow_ = (qg & 1) * 4 + (qg >> 1) * 2 + r4;                \
            __half2 lo_ = __floats2half2_rn(px0[r4], px1[r4]);                  \
            __half2 hi_ = __floats2half2_rn(px2[r4], px3[r4]);                  \
            uint2 pk_;                                                          \
            pk_.x = __builtin_bit_cast(unsigned, lo_);                          \
            pk_.y = __builtin_bit_cast(unsigned, hi_);                          \
            *(uint2*)(gd_ + grow_ * 1040) = pk_;                                \
        }                                                                       \
    } while (0)

#define PSTEP(TT) do {                                                          \
        const int t_ = (TT);                                                    \
        const char* rp_ = hist + (((t_ + 15) & 15) * 1280);                     \
        const char* gq_ = gb0 + (((t_ >> 1) & 1) * 8320) + (((t_ & 1) * 4 + qg) * 1040) + 8 * j; \
        uint2 xq_ = *(const uint2*)gq_;                                         \
        f16x8 a0_ = *(const f16x8*)(rp_ + ro0);                                 \
        f16x8 a1_ = *(const f16x8*)(rp_ + ro1);                                 \
        f16x8 a2_ = *(const f16x8*)(rp_ + ro2);                                 \
        f16x8 a3_ = *(const f16x8*)(rp_ + ro3);                                 \
        float2 flo = __half22float2(__builtin_bit_cast(__half2, xq_.x));        \
        float2 fhi = __half22float2(__builtin_bit_cast(__half2, xq_.y));        \
        f32x4 ac0 = (f32x4){flo.x, 0.f, 0.f, 0.f};                              \
        f32x4 ac1 = (f32x4){flo.y, 0.f, 0.f, 0.f};                              \
        f32x4 ac2 = (f32x4){fhi.x, 0.f, 0.f, 0.f};                              \
        f32x4 ac3 = (f32x4){fhi.y, 0.f, 0.f, 0.f};                              \
        MF4(a0_, wb, 0) MF4(a1_, wb, 1) MF4(a2_, wb, 2) MF4(a3_, wb, 3)         \
        __half hh_ = cell_update(ac0[0], ac1[0], ac2[0], ac3[0], c);            \
        *(__half*)(hist + ((t_ & 15) * 1280 + qg * 320 + j * 2)) = hh_;         \
        if ((t_ & 7) == 7) {                                                    \
            asm volatile("s_waitcnt vmcnt(0)" ::: "memory");                    \
            if (lane == 0) store_flag_sc(pflag, (unsigned)(t_ + 1));            \
        }                                                                       \
        lds_barrier();                                                          \
    } while (0)

// pair of steps with xp0 burst for the NEXT 2-step chunk (region-guarded)
#define PAIR(K) do {                                                            \
        const int te_ = tb + (K);                                               \
        if (te_ + 2 < 512 && ((te_) & 127) != 126) XP0B((te_ >> 1) + 1);        \
        PSTEP(te_); PSTEP(te_ + 1);                                             \
    } while (0)

        for (int xc = 0; xc < 4; ++xc) {
#pragma unroll 1
            for (int b4 = 0; b4 < 2; ++b4) {
                const float* src = x + ((size_t)(g * 2 + b4) * T_ + xc * 128) * 30;
                for (int idx = tid; idx < 3840; idx += 512) {
                    int tt = idx / 30, ii = idx - tt * 30;
                    xl[b4][tt][ii] = __float2half(src[idx]);
                }
            }
            __syncthreads();
            XP0B(xc * 64);           // first 2-step chunk of this region
            lds_barrier();
#pragma unroll 1
            for (int sc = 0; sc < 8; ++sc) {
                const int cc = xc * 8 + sc;
                if (cc > 0) xp1_gemm(cc - 1);
                const int tb = cc * 16;
                PAIR(0);  PAIR(2);  PAIR(4);  PAIR(6);
                PAIR(8);  PAIR(10); PAIR(12); PAIR(14);
            }
        }
        xp1_gemm(31);
        asm volatile("s_waitcnt vmcnt(0)" ::: "memory");
        if (lane == 0) store_flag_sc(pflag, 999u);
    } else {
        // ================= consumer: layer-1 recurrence (unchanged) =================
        f16x8 wb[4][4];
#pragma unroll
        for (int q = 0; q < 4; ++q)
#pragma unroll
            for (int kt = 0; kt < 4; ++kt) {
                wb[q][kt] = *reinterpret_cast<const f16x8*>(Whh1h + (size_t)(q * 128 + j) * 128 + kt * 32 + qg * 8);
                PINV(wb[q][kt]);
            }
        const int b = g * 2 + (qg & 1);          // duplicate lanes qg 2-3
        const bool wrl = qg < 2;                 // gate global h2 stores
        const uint64_t xpcb = (uint64_t)(uintptr_t)xp + ((uint64_t)(((size_t)b * T_) * 512 + 4 * j) << 1);
        __half* h2p = h2g + ((size_t)b * T_) * H_ + j;
        uint2 xq0, xq1, xq2, xq3, xq4, xq5, xq6, xq7;
        __syncthreads();

#define CSTEP(TT, XQ) do {                                                      \
        const int t_ = (TT);                                                    \
        const char* rp_ = (t_ & 1) ? hb1 : hb0;                                 \
        char* wp_ = (t_ & 1) ? hb0 : hb1;                                       \
        asm volatile("s_waitcnt vmcnt(15)" ::: "memory");                       \
        __builtin_amdgcn_sched_barrier(0);                                      \
        float2 flo = __half22float2(__builtin_bit_cast(__half2, XQ.x));         \
        float2 fhi = __half22float2(__builtin_bit_cast(__half2, XQ.y));         \
        LOAD8_SC(XQ, xpcb + (uint64_t)(t_ + 8) * 1024);                         \
        f16x8 a0_ = *(const f16x8*)(rp_ + ro0);                                 \
        f16x8 a1_ = *(const f16x8*)(rp_ + ro1);                                 \
        f16x8 a2_ = *(const f16x8*)(rp_ + ro2);                                 \
        f16x8 a3_ = *(const f16x8*)(rp_ + ro3);                                 \
        f32x4 ac0 = (f32x4){flo.x, 0.f, 0.f, 0.f};                              \
        f32x4 ac1 = (f32x4){flo.y, 0.f, 0.f, 0.f};                              \
        f32x4 ac2 = (f32x4){fhi.x, 0.f, 0.f, 0.f};                              \
        f32x4 ac3 = (f32x4){fhi.y, 0.f, 0.f, 0.f};                              \
        MF4(a0_, wb, 0) MF4(a1_, wb, 1) MF4(a2_, wb, 2) MF4(a3_, wb, 3)         \
        __half hh_ = cell_update(ac0[0], ac1[0], ac2[0], ac3[0], c);            \
        *(__half*)(wp_ + wo) = hh_;                                             \
        if (wrl) h2p[(size_t)t_ * H_] = hh_;                                    \
        lds_barrier();                                                          \
    } while (0)

        for (int tg = 0; tg < T_; tg += 16) {
            unsigned target = (tg + 40 <= 512) ? (unsigned)(tg + 40) : 999u;
            poll_min8(flagbase, target, lane);
            if (tg == 0) {
                LOAD8_SC(xq0, xpcb + 0 * 1024); LOAD8_SC(xq1, xpcb + 1 * 1024);
                LOAD8_SC(xq2, xpcb + 2 * 1024); LOAD8_SC(xq3, xpcb + 3 * 1024);
                LOAD8_SC(xq4, xpcb + 4 * 1024); LOAD8_SC(xq5, xpcb + 5 * 1024);
                LOAD8_SC(xq6, xpcb + 6 * 1024); LOAD8_SC(xq7, xpcb + 7 * 1024);
                asm volatile("s_waitcnt vmcnt(0)" ::: "memory");
                __builtin_amdgcn_sched_barrier(0);
            }
            CSTEP(tg + 0, xq0);  CSTEP(tg + 1, xq1);  CSTEP(tg + 2, xq2);  CSTEP(tg + 3, xq3);
            CSTEP(tg + 4, xq4);  CSTEP(tg + 5, xq5);  CSTEP(tg + 6, xq6);  CSTEP(tg + 7, xq7);
            CSTEP(tg + 8, xq0);  CSTEP(tg + 9, xq1);  CSTEP(tg + 10, xq2); CSTEP(tg + 11, xq3);
            CSTEP(tg + 12, xq4); CSTEP(tg + 13, xq5); CSTEP(tg + 14, xq6); CSTEP(tg + 15, xq7);
        }
    }
}

// ---------- head: out = h2 @ Wc^T + bc (63 cols, f32) ----------
__global__ __launch_bounds__(256, 4)
void head_kernel(const __half* __restrict__ in, const __half* __restrict__ W16,
                 const float* __restrict__ bias, float* __restrict__ outp)
{
    constexpr int KK = 128;
    const int lane = threadIdx.x & 63;
    const int wn = threadIdx.x >> 6;
    const int rowbase = blockIdx.x * 64;
    const int colbase = wn * 16;
    const int l15 = lane & 15, lk = (lane >> 4) * 8;

    float bcol = bias[colbase + l15];
    f32x4 acc[4];
#pragma unroll
    for (int rt = 0; rt < 4; ++rt) acc[rt] = (f32x4){0.f, 0.f, 0.f, 0.f};

#pragma unroll
    for (int kt = 0; kt < 4; ++kt) {
        f16x8 bv = *reinterpret_cast<const f16x8*>(W16 + (size_t)(colbase + l15) * KK + kt * 32 + lk);
#pragma unroll
        for (int rt = 0; rt < 4; ++rt) {
            f16x8 a = *reinterpret_cast<const f16x8*>(in + (size_t)(rowbase + rt * 16 + l15) * KK + kt * 32 + lk);
            acc[rt] = __builtin_amdgcn_mfma_f32_16x16x32_f16(a, bv, acc[rt], 0, 0, 0);
        }
    }
    const int col = colbase + l15;
#pragma unroll
    for (int rt = 0; rt < 4; ++rt)
#pragma unroll
        for (int rr = 0; rr < 4; ++rr) {
            const int row = rowbase + rt * 16 + (lane >> 4) * 4 + rr;
            if (col < 63) outp[(size_t)row * 63 + col] = acc[rt][rr] + bcol;
        }
}

extern "C" void kernel_launch(void* const* d_in, const int* in_sizes, int n_in,
                              void* d_out, int out_size, void* d_ws, size_t ws_size,
                              hipStream_t stream)
{
    const float* x    = (const float*)d_in[0];
    const float* Wih0 = (const float*)d_in[1];
    const float* Whh0 = (const float*)d_in[2];
    const float* bih0 = (const float*)d_in[3];
    const float* bhh0 = (const float*)d_in[4];
    const float* Wih1 = (const float*)d_in[5];
    const float* Whh1 = (const float*)d_in[6];
    const float* bih1 = (const float*)d_in[7];
    const float* bhh1 = (const float*)d_in[8];
    const float* Wl   = (const float*)d_in[9];
    const float* bl   = (const float*)d_in[10];
    const float* Wo   = (const float*)d_in[11];
    const float* bo   = (const float*)d_in[12];
    float* out = (float*)d_out;

    char* ws = (char*)d_ws;
    size_t off = 0;
    auto carve = [&](size_t bytes) { void* p = ws + off; off += (bytes + 255) & ~(size_t)255; return p; };
    __half* xp    = (__half*)carve((size_t)M_ * 512 * 2 + 16384);  // gate stream + prefetch pad
    __half* h2    = (__half*)carve((size_t)M_ * 128 * 2);          // 33.5 MB
    __half* W0b   = (__half*)carve(512 * 32 * 2);
    __half* W1b   = (__half*)carve(512 * 128 * 2);
    __half* Whh0h = (__half*)carve(512 * 128 * 2);
    __half* Whh1h = (__half*)carve(512 * 128 * 2);
    __half* Wc16  = (__half*)carve(64 * 128 * 2);
    float*  b0    = (float*)carve(512 * 4);
    float*  b1    = (float*)carve(512 * 4);
    float*  bc    = (float*)carve(64 * 4);
    unsigned* flags = (unsigned*)carve(2048 * 4);

    hipLaunchKernelGGL(convert_kernel, dim3(17), dim3(256), 0, stream,
                       Wih0, bih0, bhh0, Whh0, Wih1, Whh1, bih1, bhh1, Wl, bl, Wo, bo,
                       W0b, W1b, Whh0h, Whh1h, Wc16, b0, b1, bc);

    hipMemsetAsync(flags, 0, 2048 * 4, stream);  // flags must start at 0 every replay

    hipLaunchKernelGGL(lstm_fused, dim3(256), dim3(512), 0, stream,
                       x, W0b, Whh0h, W1b, Whh1h, b0, b1, xp, h2, flags);

    hipLaunchKernelGGL(head_kernel, dim3(M_ / 64), dim3(256), 0, stream,
                       h2, Wc16, bc, out);
}